// Round 16
// baseline (184.944 us; speedup 1.0000x reference)
//
#include <hip/hip_runtime.h>
#include <hip/hip_bf16.h>

// B=4, N=1024, DIM=768, H=12, Dh=64.
// ws layout (bf16 = short):
//   qkvb : [4096][2304]              18.9 MB
//   S    : [4][12][1024][1024]      100.7 MB   (scores -> mixed P', in place)
//   vT   : [4][12][64][1024]          6.3 MB
//   ao   : [4096][768]                6.3 MB

#define NSEQ 1024
#define NH 12

typedef __attribute__((ext_vector_type(8))) short bf16x8;
typedef __attribute__((ext_vector_type(4))) float f32x4;
typedef __attribute__((ext_vector_type(2))) float f32x2;

static __device__ __forceinline__ short f2b(float f) {
    union { __hip_bfloat16 h; short s; } u;
    u.h = __float2bfloat16(f);
    return u.s;
}
static __device__ __forceinline__ float b2f(short s) {
    union { unsigned u; float f; } v;
    v.u = ((unsigned)(unsigned short)s) << 16;
    return v.f;
}

// ---------------------------------------------------------------------------
// bf16 MFMA NT GEMM: C[i][j] = alpha*sum_k A[i][k]*B[j][k] (+bias[j]).
// A: [M][K] row-major (fp32 or bf16; fp32 cast during LDS staging).
// B: [N][K] row-major. C: fp32 or bf16 row-major.
// Tile BMxBN, 256 threads = 4 waves in 2x2; 16x16x32 MFMA. BK=32.
// ---------------------------------------------------------------------------
template<int BM, int BN, bool AF32, bool BF32, bool OUTF32, bool BIAS>
__global__ __launch_bounds__(256) void gemm_mfma(
    const void* __restrict__ Av, const void* __restrict__ Bv, void* __restrict__ Cv,
    int lda, int ldb, int ldc, int K, int zdiv,
    long long sA1, long long sA2, long long sB1, long long sB2,
    long long sC1, long long sC2,
    const float* __restrict__ bias, float alpha)
{
    constexpr int BKP = 40;
    constexpr int AC = BM / 64;
    constexpr int BC = BN / 64;
    constexpr int FM = BM / 32;
    constexpr int FN = BN / 32;

    __shared__ short As[BM * BKP];
    __shared__ short Bs[BN * BKP];

    const int z = blockIdx.z, z1 = z / zdiv, z2 = z % zdiv;
    const long long offA = (long long)z1 * sA1 + (long long)z2 * sA2;
    const long long offB = (long long)z1 * sB1 + (long long)z2 * sB2;
    const long long offC = (long long)z1 * sC1 + (long long)z2 * sC2;

    const int tid = threadIdx.x;
    const int lane = tid & 63, wid = tid >> 6;
    const int wr = wid >> 1, wc = wid & 1;
    const int m0 = blockIdx.y * BM, n0 = blockIdx.x * BN;

    const int arow = wr * (BM / 2) + (lane & 15);
    const int brow = wc * (BN / 2) + (lane & 15);
    const int kb = (lane >> 4) * 8;

    f32x4 acc[FM][FN] = {};

    for (int k0 = 0; k0 < K; k0 += 32) {
        float4 a0[AC], a1[AC]; bf16x8 ah[AC];
        float4 b0[BC], b1[BC]; bf16x8 bh[BC];
#pragma unroll
        for (int i = 0; i < AC; ++i) {
            const int c = tid + 256 * i;
            const long long e = offA + (long long)(m0 + (c >> 2)) * lda + k0 + (c & 3) * 8;
            if constexpr (AF32) {
                const float* p = (const float*)Av + e;
                a0[i] = *(const float4*)p; a1[i] = *(const float4*)(p + 4);
            } else {
                ah[i] = *(const bf16x8*)((const short*)Av + e);
            }
        }
#pragma unroll
        for (int i = 0; i < BC; ++i) {
            const int c = tid + 256 * i;
            const long long e = offB + (long long)(n0 + (c >> 2)) * ldb + k0 + (c & 3) * 8;
            if constexpr (BF32) {
                const float* p = (const float*)Bv + e;
                b0[i] = *(const float4*)p; b1[i] = *(const float4*)(p + 4);
            } else {
                bh[i] = *(const bf16x8*)((const short*)Bv + e);
            }
        }
        __syncthreads();
#pragma unroll
        for (int i = 0; i < AC; ++i) {
            const int c = tid + 256 * i;
            short* dst = &As[(c >> 2) * BKP + (c & 3) * 8];
            if constexpr (AF32) {
                bf16x8 v;
                v[0] = f2b(a0[i].x); v[1] = f2b(a0[i].y); v[2] = f2b(a0[i].z); v[3] = f2b(a0[i].w);
                v[4] = f2b(a1[i].x); v[5] = f2b(a1[i].y); v[6] = f2b(a1[i].z); v[7] = f2b(a1[i].w);
                *(bf16x8*)dst = v;
            } else {
                *(bf16x8*)dst = ah[i];
            }
        }
#pragma unroll
        for (int i = 0; i < BC; ++i) {
            const int c = tid + 256 * i;
            short* dst = &Bs[(c >> 2) * BKP + (c & 3) * 8];
            if constexpr (BF32) {
                bf16x8 v;
                v[0] = f2b(b0[i].x); v[1] = f2b(b0[i].y); v[2] = f2b(b0[i].z); v[3] = f2b(b0[i].w);
                v[4] = f2b(b1[i].x); v[5] = f2b(b1[i].y); v[6] = f2b(b1[i].z); v[7] = f2b(b1[i].w);
                *(bf16x8*)dst = v;
            } else {
                *(bf16x8*)dst = bh[i];
            }
        }
        __syncthreads();
        bf16x8 af[FM], bfr[FN];
#pragma unroll
        for (int i = 0; i < FM; ++i)
            af[i] = *(const bf16x8*)&As[(arow + i * 16) * BKP + kb];
#pragma unroll
        for (int j = 0; j < FN; ++j)
            bfr[j] = *(const bf16x8*)&Bs[(brow + j * 16) * BKP + kb];
#pragma unroll
        for (int i = 0; i < FM; ++i)
#pragma unroll
            for (int j = 0; j < FN; ++j)
                acc[i][j] = __builtin_amdgcn_mfma_f32_16x16x32_bf16(
                    af[i], bfr[j], acc[i][j], 0, 0, 0);
    }

    const int crow0 = m0 + wr * (BM / 2) + (lane >> 4) * 4;
    const int ccol0 = n0 + wc * (BN / 2) + (lane & 15);
#pragma unroll
    for (int j = 0; j < FN; ++j) {
        const int col = ccol0 + j * 16;
        float badd = 0.f;
        if constexpr (BIAS) badd = bias[col];
#pragma unroll
        for (int i = 0; i < FM; ++i) {
#pragma unroll
            for (int r = 0; r < 4; ++r) {
                const int row = crow0 + i * 16 + r;
                const long long off = offC + (long long)row * ldc + col;
                const float vv = acc[i][j][r] * alpha + badd;
                if constexpr (OUTF32) ((float*)Cv)[off] = vv;
                else                  ((short*)Cv)[off] = f2b(vv);
            }
        }
    }
}

// ---------------------------------------------------------------------------
// v transpose: qkvb bf16 [B*N][2304] (v at col 1536+h*64) -> vT [48][64][1024]
// ---------------------------------------------------------------------------
__global__ __launch_bounds__(256) void vtrans(
    const short* __restrict__ qkvb, short* __restrict__ vT)
{
    __shared__ short t[64][72];
    const int bh = blockIdx.y;
    const int m0 = blockIdx.x * 64;
    const long long src0 = ((long long)(bh / 12) * 1024 + m0) * 2304 + 1536 + (bh % 12) * 64;
#pragma unroll
    for (int i = 0; i < 2; ++i) {
        const int c = threadIdx.x + 256 * i;
        const int m = c >> 3, dc = (c & 7) * 8;
        bf16x8 v = *(const bf16x8*)(qkvb + src0 + (long long)m * 2304 + dc);
#pragma unroll
        for (int j = 0; j < 8; ++j) t[dc + j][m] = v[j];
    }
    __syncthreads();
#pragma unroll
    for (int i = 0; i < 2; ++i) {
        const int c = threadIdx.x + 256 * i;
        const int d = c >> 3, mc = (c & 7) * 8;
        bf16x8 v;
#pragma unroll
        for (int j = 0; j < 8; ++j) v[j] = t[d][mc + j];
        *(bf16x8*)(vT + ((long long)bh * 64 + d) * 1024 + m0 + mc) = v;
    }
}

// ---------------------------------------------------------------------------
// Register-resident mix/softmax (r13-proven shape: 256 thr = 2 rows/block,
// 8 cols/thread as FOUR float2 vectors, 16B/lane I/O, no-max softmax).
// Mix math expressed via __builtin_elementwise_fma on f32x2 so the compiler
// can emit v_pk_fma_f32 (2x VALU rate). Per-component arithmetic and
// summation order identical to the scalar r13 kernel.
// ---------------------------------------------------------------------------
__global__ __launch_bounds__(256, 2) void mix_softmax(
    short* __restrict__ S,
    const float* __restrict__ Wl, const float* __restrict__ bl,
    const float* __restrict__ Ww, const float* __restrict__ bw,
    const float* __restrict__ lamb)
{
    const int tid = threadIdx.x;
    const int t = tid & 127;            // column-group within row
    const int half = tid >> 7;          // which of the 2 rows
    const int lane = tid & 63;
    const int wv = (tid >> 6) & 1;      // wave index within the row (0,1)
    const int n = blockIdx.x * 2 + half;
    const int b = blockIdx.y;

    __shared__ float wl[NH * NH], ww[NH * NH];
    __shared__ float blv[NH], cc0[NH], cc1[NH];
    __shared__ float red[2][NH][2];
    __shared__ float rinv[2][NH];

    if (tid < NH * NH) { wl[tid] = Wl[tid]; ww[tid] = Ww[tid]; }
    if (tid < NH) {
        blv[tid] = bl[tid];
        const float lam = lamb[tid];
        cc1[tid] = 1.0f + lam;
        cc0[tid] = (1.0f + lam) * bw[tid] - lam * (1.0f / (float)NSEQ);
    }
    __syncthreads();

    const long long base = ((long long)(b * NH) * NSEQ + n) * NSEQ + t * 8;

    // ---- load 12 heads x 8 cols (4 x float2), 16B per load ----
    f32x2 s2[NH][4];
#pragma unroll
    for (int h = 0; h < NH; ++h) {
        bf16x8 v = *(const bf16x8*)(S + base + (long long)h * NSEQ * NSEQ);
#pragma unroll
        for (int j = 0; j < 4; ++j) {
            s2[h][j][0] = b2f(v[2 * j + 0]);
            s2[h][j][1] = b2f(v[2 * j + 1]);
        }
    }

    // ---- pre-mix across heads, two 2-vector sub-blocks (caps VGPR) ----
#pragma unroll
    for (int vb = 0; vb < 4; vb += 2) {
        f32x2 o2[NH][2];
#pragma unroll
        for (int g = 0; g < NH; ++g) {
            f32x2 a0; a0[0] = blv[g]; a0[1] = blv[g];
            f32x2 a1 = a0;
#pragma unroll
            for (int h = 0; h < NH; ++h) {
                const float w = wl[g * NH + h];
                f32x2 w2; w2[0] = w; w2[1] = w;
                a0 = __builtin_elementwise_fma(s2[h][vb + 0], w2, a0);
                a1 = __builtin_elementwise_fma(s2[h][vb + 1], w2, a1);
            }
            o2[g][0] = a0; o2[g][1] = a1;
        }
#pragma unroll
        for (int g = 0; g < NH; ++g) {
            s2[g][vb + 0] = o2[g][0];
            s2[g][vb + 1] = o2[g][1];
        }
    }

    // ---- exp (no max subtraction) + row sum ----
#pragma unroll
    for (int g = 0; g < NH; ++g) {
#pragma unroll
        for (int j = 0; j < 4; ++j) {
            s2[g][j][0] = __expf(s2[g][j][0]);
            s2[g][j][1] = __expf(s2[g][j][1]);
        }
        float v = ((s2[g][0][0] + s2[g][0][1]) + (s2[g][1][0] + s2[g][1][1])) +
                  ((s2[g][2][0] + s2[g][2][1]) + (s2[g][3][0] + s2[g][3][1]));
#pragma unroll
        for (int off = 1; off < 64; off <<= 1)
            v += __shfl_xor(v, off, 64);
        if (lane == 0) red[half][g][wv] = v;
    }
    __syncthreads();
    if (tid < 2 * NH) {
        const int hh = tid >= NH ? 1 : 0;
        const int g = tid - hh * NH;
        rinv[hh][g] = 1.0f / (red[hh][g][0] + red[hh][g][1]);
    }
    __syncthreads();

    // ---- normalize in regs ----
#pragma unroll
    for (int h = 0; h < NH; ++h) {
        const float inv = rinv[half][h];
        f32x2 inv2; inv2[0] = inv; inv2[1] = inv;
#pragma unroll
        for (int j = 0; j < 4; ++j) s2[h][j] *= inv2;
    }

    // ---- post-mix + attnscale, 16B stores ----
#pragma unroll
    for (int g = 0; g < NH; ++g) {
        f32x2 a[4];
#pragma unroll
        for (int j = 0; j < 4; ++j) { a[j][0] = 0.f; a[j][1] = 0.f; }
#pragma unroll
        for (int h = 0; h < NH; ++h) {
            const float w = ww[g * NH + h];
            f32x2 w2; w2[0] = w; w2[1] = w;
#pragma unroll
            for (int j = 0; j < 4; ++j)
                a[j] = __builtin_elementwise_fma(s2[h][j], w2, a[j]);
        }
        const float c1 = cc1[g], c0 = cc0[g];
        bf16x8 ov;
#pragma unroll
        for (int j = 0; j < 4; ++j) {
            ov[2 * j + 0] = f2b(fmaf(c1, a[j][0], c0));
            ov[2 * j + 1] = f2b(fmaf(c1, a[j][1], c0));
        }
        *(bf16x8*)(S + base + (long long)g * NSEQ * NSEQ) = ov;
    }
}

extern "C" void kernel_launch(void* const* d_in, const int* in_sizes, int n_in,
                              void* d_out, int out_size, void* d_ws, size_t ws_size,
                              hipStream_t stream) {
    const float* x     = (const float*)d_in[0];
    const float* Wqkv  = (const float*)d_in[1];
    const float* Wproj = (const float*)d_in[2];
    const float* bproj = (const float*)d_in[3];
    const float* Wl    = (const float*)d_in[4];
    const float* bl    = (const float*)d_in[5];
    const float* Ww    = (const float*)d_in[6];
    const float* bw    = (const float*)d_in[7];
    const float* lamb  = (const float*)d_in[8];
    float* out = (float*)d_out;

    short* qkvb = (short*)d_ws;                        // [4096][2304]
    short* S    = qkvb + (size_t)4096 * 2304;          // [48][1024][1024]
    short* vT   = S + (size_t)48 * 1024 * 1024;        // [48][64][1024]
    short* ao   = vT + (size_t)48 * 64 * 1024;         // [4096][768]

    // 1. qkvb = bf16(x @ Wqkv^T)
    gemm_mfma<128, 128, true, true, false, false>
        <<<dim3(18, 32, 1), 256, 0, stream>>>(
        x, Wqkv, qkvb, 768, 768, 2304, 768, 1,
        0, 0, 0, 0, 0, 0, nullptr, 1.0f);

    // 2. vT = transpose of v-slice of qkvb
    vtrans<<<dim3(16, 48, 1), 256, 0, stream>>>(qkvb, vT);

    // 3. S = bf16(SCALE * q k^T) per (b,h)
    gemm_mfma<128, 128, false, false, false, false>
        <<<dim3(8, 8, 48), 256, 0, stream>>>(
        qkvb, qkvb + 768, S, 2304, 2304, 1024, 64, 12,
        2304LL * 1024, 64, 2304LL * 1024, 64,
        12LL * 1024 * 1024, 1024LL * 1024, nullptr, 0.125f);

    // 4. talking-heads pre -> softmax(no-max) -> post -> attnscale (in place)
    mix_softmax<<<dim3(512, 4, 1), 256, 0, stream>>>(S, Wl, bl, Ww, bw, lamb);

    // 5. ao[b,n,h*64+d] = sum_m P'[b,h,n,m] vT[b,h,d,m]
    gemm_mfma<64, 64, false, false, false, false>
        <<<dim3(1, 16, 48), 256, 0, stream>>>(
        S, vT, ao, 1024, 1024, 768, 1024, 12,
        12LL * 1024 * 1024, 1024LL * 1024,
        12LL * 64 * 1024, 64LL * 1024,
        1024LL * 768, 64, nullptr, 1.0f);

    // 6. out = ao @ Wproj^T + bproj  (64x64 tiles: 768 blocks = 3/CU)
    gemm_mfma<64, 64, false, true, true, true>
        <<<dim3(12, 64, 1), 256, 0, stream>>>(
        ao, Wproj, out, 768, 768, 768, 768, 1,
        0, 0, 0, 0, 0, 0, bproj, 1.0f);
}

// Round 17
// 178.979 us; speedup vs baseline: 1.0333x; 1.0333x over previous
//
#include <hip/hip_runtime.h>
#include <hip/hip_bf16.h>

// B=4, N=1024, DIM=768, H=12, Dh=64.
// ws layout (bf16 = short):
//   qkvb : [4096][2304]              18.9 MB
//   S    : [4][12][1024][1024]      100.7 MB   (scores -> mixed P', in place)
//   vT   : [4][12][64][1024]          6.3 MB
//   ao   : [4096][768]                6.3 MB

#define NSEQ 1024
#define NH 12

typedef __attribute__((ext_vector_type(8))) short bf16x8;
typedef __attribute__((ext_vector_type(4))) float f32x4;

#if __has_builtin(__builtin_amdgcn_exp2f)
#define EXP2(x) __builtin_amdgcn_exp2f(x)
#else
#define EXP2(x) exp2f(x)
#endif
#define LOG2E 1.44269504088896340736f

static __device__ __forceinline__ short f2b(float f) {
    union { __hip_bfloat16 h; short s; } u;
    u.h = __float2bfloat16(f);
    return u.s;
}
static __device__ __forceinline__ float b2f(short s) {
    union { unsigned u; float f; } v;
    v.u = ((unsigned)(unsigned short)s) << 16;
    return v.f;
}

// ---------------------------------------------------------------------------
// bf16 MFMA NT GEMM: C[i][j] = alpha*sum_k A[i][k]*B[j][k] (+bias[j]).
// A: [M][K] row-major (fp32 or bf16; fp32 cast during LDS staging).
// B: [N][K] row-major. C: fp32 or bf16 row-major.
// Tile BMxBN, 256 threads = 4 waves in 2x2; 16x16x32 MFMA. BK=32.
// ---------------------------------------------------------------------------
template<int BM, int BN, bool AF32, bool BF32, bool OUTF32, bool BIAS>
__global__ __launch_bounds__(256) void gemm_mfma(
    const void* __restrict__ Av, const void* __restrict__ Bv, void* __restrict__ Cv,
    int lda, int ldb, int ldc, int K, int zdiv,
    long long sA1, long long sA2, long long sB1, long long sB2,
    long long sC1, long long sC2,
    const float* __restrict__ bias, float alpha)
{
    constexpr int BKP = 40;
    constexpr int AC = BM / 64;
    constexpr int BC = BN / 64;
    constexpr int FM = BM / 32;
    constexpr int FN = BN / 32;

    __shared__ short As[BM * BKP];
    __shared__ short Bs[BN * BKP];

    const int z = blockIdx.z, z1 = z / zdiv, z2 = z % zdiv;
    const long long offA = (long long)z1 * sA1 + (long long)z2 * sA2;
    const long long offB = (long long)z1 * sB1 + (long long)z2 * sB2;
    const long long offC = (long long)z1 * sC1 + (long long)z2 * sC2;

    const int tid = threadIdx.x;
    const int lane = tid & 63, wid = tid >> 6;
    const int wr = wid >> 1, wc = wid & 1;
    const int m0 = blockIdx.y * BM, n0 = blockIdx.x * BN;

    const int arow = wr * (BM / 2) + (lane & 15);
    const int brow = wc * (BN / 2) + (lane & 15);
    const int kb = (lane >> 4) * 8;

    f32x4 acc[FM][FN] = {};

    for (int k0 = 0; k0 < K; k0 += 32) {
        float4 a0[AC], a1[AC]; bf16x8 ah[AC];
        float4 b0[BC], b1[BC]; bf16x8 bh[BC];
#pragma unroll
        for (int i = 0; i < AC; ++i) {
            const int c = tid + 256 * i;
            const long long e = offA + (long long)(m0 + (c >> 2)) * lda + k0 + (c & 3) * 8;
            if constexpr (AF32) {
                const float* p = (const float*)Av + e;
                a0[i] = *(const float4*)p; a1[i] = *(const float4*)(p + 4);
            } else {
                ah[i] = *(const bf16x8*)((const short*)Av + e);
            }
        }
#pragma unroll
        for (int i = 0; i < BC; ++i) {
            const int c = tid + 256 * i;
            const long long e = offB + (long long)(n0 + (c >> 2)) * ldb + k0 + (c & 3) * 8;
            if constexpr (BF32) {
                const float* p = (const float*)Bv + e;
                b0[i] = *(const float4*)p; b1[i] = *(const float4*)(p + 4);
            } else {
                bh[i] = *(const bf16x8*)((const short*)Bv + e);
            }
        }
        __syncthreads();
#pragma unroll
        for (int i = 0; i < AC; ++i) {
            const int c = tid + 256 * i;
            short* dst = &As[(c >> 2) * BKP + (c & 3) * 8];
            if constexpr (AF32) {
                bf16x8 v;
                v[0] = f2b(a0[i].x); v[1] = f2b(a0[i].y); v[2] = f2b(a0[i].z); v[3] = f2b(a0[i].w);
                v[4] = f2b(a1[i].x); v[5] = f2b(a1[i].y); v[6] = f2b(a1[i].z); v[7] = f2b(a1[i].w);
                *(bf16x8*)dst = v;
            } else {
                *(bf16x8*)dst = ah[i];
            }
        }
#pragma unroll
        for (int i = 0; i < BC; ++i) {
            const int c = tid + 256 * i;
            short* dst = &Bs[(c >> 2) * BKP + (c & 3) * 8];
            if constexpr (BF32) {
                bf16x8 v;
                v[0] = f2b(b0[i].x); v[1] = f2b(b0[i].y); v[2] = f2b(b0[i].z); v[3] = f2b(b0[i].w);
                v[4] = f2b(b1[i].x); v[5] = f2b(b1[i].y); v[6] = f2b(b1[i].z); v[7] = f2b(b1[i].w);
                *(bf16x8*)dst = v;
            } else {
                *(bf16x8*)dst = bh[i];
            }
        }
        __syncthreads();
        bf16x8 af[FM], bfr[FN];
#pragma unroll
        for (int i = 0; i < FM; ++i)
            af[i] = *(const bf16x8*)&As[(arow + i * 16) * BKP + kb];
#pragma unroll
        for (int j = 0; j < FN; ++j)
            bfr[j] = *(const bf16x8*)&Bs[(brow + j * 16) * BKP + kb];
#pragma unroll
        for (int i = 0; i < FM; ++i)
#pragma unroll
            for (int j = 0; j < FN; ++j)
                acc[i][j] = __builtin_amdgcn_mfma_f32_16x16x32_bf16(
                    af[i], bfr[j], acc[i][j], 0, 0, 0);
    }

    const int crow0 = m0 + wr * (BM / 2) + (lane >> 4) * 4;
    const int ccol0 = n0 + wc * (BN / 2) + (lane & 15);
#pragma unroll
    for (int j = 0; j < FN; ++j) {
        const int col = ccol0 + j * 16;
        float badd = 0.f;
        if constexpr (BIAS) badd = bias[col];
#pragma unroll
        for (int i = 0; i < FM; ++i) {
#pragma unroll
            for (int r = 0; r < 4; ++r) {
                const int row = crow0 + i * 16 + r;
                const long long off = offC + (long long)row * ldc + col;
                const float vv = acc[i][j][r] * alpha + badd;
                if constexpr (OUTF32) ((float*)Cv)[off] = vv;
                else                  ((short*)Cv)[off] = f2b(vv);
            }
        }
    }
}

// ---------------------------------------------------------------------------
// v transpose: qkvb bf16 [B*N][2304] (v at col 1536+h*64) -> vT [48][64][1024]
// ---------------------------------------------------------------------------
__global__ __launch_bounds__(256) void vtrans(
    const short* __restrict__ qkvb, short* __restrict__ vT)
{
    __shared__ short t[64][72];
    const int bh = blockIdx.y;
    const int m0 = blockIdx.x * 64;
    const long long src0 = ((long long)(bh / 12) * 1024 + m0) * 2304 + 1536 + (bh % 12) * 64;
#pragma unroll
    for (int i = 0; i < 2; ++i) {
        const int c = threadIdx.x + 256 * i;
        const int m = c >> 3, dc = (c & 7) * 8;
        bf16x8 v = *(const bf16x8*)(qkvb + src0 + (long long)m * 2304 + dc);
#pragma unroll
        for (int j = 0; j < 8; ++j) t[dc + j][m] = v[j];
    }
    __syncthreads();
#pragma unroll
    for (int i = 0; i < 2; ++i) {
        const int c = threadIdx.x + 256 * i;
        const int d = c >> 3, mc = (c & 7) * 8;
        bf16x8 v;
#pragma unroll
        for (int j = 0; j < 8; ++j) v[j] = t[d][mc + j];
        *(bf16x8*)(vT + ((long long)bh * 64 + d) * 1024 + m0 + mc) = v;
    }
}

// ---------------------------------------------------------------------------
// Register-resident mix/softmax (r13-proven shape: 256 thr = 2 rows/block,
// 8 cols/thread, 16B/lane I/O, no-max softmax, launch_bounds (256,2)).
// Only change vs r13: log2(e) folded into premix weights/bias so exp(x)
// becomes a single native v_exp_f32 (2^x) — no per-element multiply.
// ---------------------------------------------------------------------------
__global__ __launch_bounds__(256, 2) void mix_softmax(
    short* __restrict__ S,
    const float* __restrict__ Wl, const float* __restrict__ bl,
    const float* __restrict__ Ww, const float* __restrict__ bw,
    const float* __restrict__ lamb)
{
    const int tid = threadIdx.x;
    const int t = tid & 127;            // column-group within row
    const int half = tid >> 7;          // which of the 2 rows
    const int lane = tid & 63;
    const int wv = (tid >> 6) & 1;      // wave index within the row (0,1)
    const int n = blockIdx.x * 2 + half;
    const int b = blockIdx.y;

    __shared__ float wl[NH * NH], ww[NH * NH];
    __shared__ float blv[NH], cc0[NH], cc1[NH];
    __shared__ float red[2][NH][2];
    __shared__ float rinv[2][NH];

    if (tid < NH * NH) { wl[tid] = Wl[tid] * LOG2E; ww[tid] = Ww[tid]; }
    if (tid < NH) {
        blv[tid] = bl[tid] * LOG2E;
        const float lam = lamb[tid];
        cc1[tid] = 1.0f + lam;
        cc0[tid] = (1.0f + lam) * bw[tid] - lam * (1.0f / (float)NSEQ);
    }
    __syncthreads();

    const long long base = ((long long)(b * NH) * NSEQ + n) * NSEQ + t * 8;

    // ---- load 12 heads x 8 cols, 16B per load ----
    float s[NH][8];
#pragma unroll
    for (int h = 0; h < NH; ++h) {
        bf16x8 v = *(const bf16x8*)(S + base + (long long)h * NSEQ * NSEQ);
#pragma unroll
        for (int c = 0; c < 8; ++c) s[h][c] = b2f(v[c]);
    }

    // ---- pre-mix across heads (xLOG2E), two 4-column sub-blocks ----
#pragma unroll
    for (int cb = 0; cb < 8; cb += 4) {
        float o[NH][4];
#pragma unroll
        for (int g = 0; g < NH; ++g) {
            float a0 = blv[g], a1 = a0, a2 = a0, a3 = a0;
#pragma unroll
            for (int h = 0; h < NH; ++h) {
                const float w = wl[g * NH + h];
                a0 = fmaf(s[h][cb + 0], w, a0);
                a1 = fmaf(s[h][cb + 1], w, a1);
                a2 = fmaf(s[h][cb + 2], w, a2);
                a3 = fmaf(s[h][cb + 3], w, a3);
            }
            o[g][0] = a0; o[g][1] = a1; o[g][2] = a2; o[g][3] = a3;
        }
#pragma unroll
        for (int g = 0; g < NH; ++g) {
            s[g][cb + 0] = o[g][0]; s[g][cb + 1] = o[g][1];
            s[g][cb + 2] = o[g][2]; s[g][cb + 3] = o[g][3];
        }
    }

    // ---- exp2 (log2e pre-folded; no max subtraction) + row sum ----
#pragma unroll
    for (int g = 0; g < NH; ++g) {
#pragma unroll
        for (int c = 0; c < 8; ++c) s[g][c] = EXP2(s[g][c]);
        float v = ((s[g][0] + s[g][1]) + (s[g][2] + s[g][3])) +
                  ((s[g][4] + s[g][5]) + (s[g][6] + s[g][7]));
#pragma unroll
        for (int off = 1; off < 64; off <<= 1)
            v += __shfl_xor(v, off, 64);
        if (lane == 0) red[half][g][wv] = v;
    }
    __syncthreads();
    if (tid < 2 * NH) {
        const int hh = tid >= NH ? 1 : 0;
        const int g = tid - hh * NH;
        rinv[hh][g] = 1.0f / (red[hh][g][0] + red[hh][g][1]);
    }
    __syncthreads();

    // ---- normalize in regs ----
#pragma unroll
    for (int h = 0; h < NH; ++h) {
        const float inv = rinv[half][h];
#pragma unroll
        for (int c = 0; c < 8; ++c) s[h][c] *= inv;
    }

    // ---- post-mix + attnscale, 16B stores ----
#pragma unroll
    for (int g = 0; g < NH; ++g) {
        float a[8] = {0.f, 0.f, 0.f, 0.f, 0.f, 0.f, 0.f, 0.f};
#pragma unroll
        for (int h = 0; h < NH; ++h) {
            const float w = ww[g * NH + h];
#pragma unroll
            for (int c = 0; c < 8; ++c) a[c] = fmaf(s[h][c], w, a[c]);
        }
        bf16x8 ov;
#pragma unroll
        for (int c = 0; c < 8; ++c)
            ov[c] = f2b(fmaf(cc1[g], a[c], cc0[g]));
        *(bf16x8*)(S + base + (long long)g * NSEQ * NSEQ) = ov;
    }
}

extern "C" void kernel_launch(void* const* d_in, const int* in_sizes, int n_in,
                              void* d_out, int out_size, void* d_ws, size_t ws_size,
                              hipStream_t stream) {
    const float* x     = (const float*)d_in[0];
    const float* Wqkv  = (const float*)d_in[1];
    const float* Wproj = (const float*)d_in[2];
    const float* bproj = (const float*)d_in[3];
    const float* Wl    = (const float*)d_in[4];
    const float* bl    = (const float*)d_in[5];
    const float* Ww    = (const float*)d_in[6];
    const float* bw    = (const float*)d_in[7];
    const float* lamb  = (const float*)d_in[8];
    float* out = (float*)d_out;

    short* qkvb = (short*)d_ws;                        // [4096][2304]
    short* S    = qkvb + (size_t)4096 * 2304;          // [48][1024][1024]
    short* vT   = S + (size_t)48 * 1024 * 1024;        // [48][64][1024]
    short* ao   = vT + (size_t)48 * 64 * 1024;         // [4096][768]

    // 1. qkvb = bf16(x @ Wqkv^T)
    gemm_mfma<128, 128, true, true, false, false>
        <<<dim3(18, 32, 1), 256, 0, stream>>>(
        x, Wqkv, qkvb, 768, 768, 2304, 768, 1,
        0, 0, 0, 0, 0, 0, nullptr, 1.0f);

    // 2. vT = transpose of v-slice of qkvb
    vtrans<<<dim3(16, 48, 1), 256, 0, stream>>>(qkvb, vT);

    // 3. S = bf16(SCALE * q k^T) per (b,h)
    gemm_mfma<128, 128, false, false, false, false>
        <<<dim3(8, 8, 48), 256, 0, stream>>>(
        qkvb, qkvb + 768, S, 2304, 2304, 1024, 64, 12,
        2304LL * 1024, 64, 2304LL * 1024, 64,
        12LL * 1024 * 1024, 1024LL * 1024, nullptr, 0.125f);

    // 4. talking-heads pre -> softmax(no-max, exp2) -> post -> attnscale
    mix_softmax<<<dim3(512, 4, 1), 256, 0, stream>>>(S, Wl, bl, Ww, bw, lamb);

    // 5. ao[b,n,h*64+d] = sum_m P'[b,h,n,m] vT[b,h,d,m]
    gemm_mfma<64, 64, false, false, false, false>
        <<<dim3(1, 16, 48), 256, 0, stream>>>(
        S, vT, ao, 1024, 1024, 768, 1024, 12,
        12LL * 1024 * 1024, 1024LL * 1024,
        12LL * 64 * 1024, 64LL * 1024,
        1024LL * 768, 64, nullptr, 1.0f);

    // 6. out = ao @ Wproj^T + bproj  (64x64 tiles: 768 blocks = 3/CU)
    gemm_mfma<64, 64, false, true, true, true>
        <<<dim3(12, 64, 1), 256, 0, stream>>>(
        ao, Wproj, out, 768, 768, 768, 768, 1,
        0, 0, 0, 0, 0, 0, bproj, 1.0f);
}